// Round 4
// baseline (638.858 us; speedup 1.0000x reference)
//
#include <hip/hip_runtime.h>

typedef __attribute__((ext_vector_type(8))) short short8;    // 8 bf16 = 4 VGPRs
typedef __attribute__((ext_vector_type(4))) float float4v;   // MFMA acc

static __device__ __forceinline__ unsigned short f2bf(float x) {
    unsigned u = __float_as_uint(x);
    return (unsigned short)((u + 0x7fffu + ((u >> 16) & 1u)) >> 16);  // RNE
}
static __device__ __forceinline__ int imin(int a, int b) { return a < b ? a : b; }
static __device__ __forceinline__ int imax(int a, int b) { return a > b ? a : b; }

// async global->LDS, 16B per lane; LDS dest is wave-uniform base + lane*16
static __device__ __forceinline__ void gload_lds16(const void* g, void* l) {
    __builtin_amdgcn_global_load_lds(
        (const __attribute__((address_space(1))) void*)g,
        (__attribute__((address_space(3))) void*)l, 16, 0, 0);
}

// ---------------------------------------------------------------------------
// Kernel 0: repack conv weights fp32 -> bf16, [cin_chunk8][tap9][cout128][cin32]
//           + zero the 64B OOB guard block.
// ---------------------------------------------------------------------------
__global__ void wprep_kernel(const float* __restrict__ conv_w,
                             unsigned short* __restrict__ wprep,
                             unsigned short* __restrict__ zguard) {
    if (blockIdx.x == 0 && threadIdx.x < 32) zguard[threadIdx.x] = 0;
    int e = blockIdx.x * 256 + threadIdx.x;           // 294912 total
    if (e >= 294912) return;
    int ci = e & 31;
    int t2 = e >> 5;
    int co = t2 & 127;
    int t3 = t2 >> 7;        // chunk*9 + tap
    int tap = t3 % 9;
    int chunk = t3 / 9;
    int cin = chunk * 32 + ci;
    int ty = tap / 3, tx = tap - ty * 3;
    wprep[e] = f2bf(conv_w[((co * 256 + cin) * 3 + ty) * 3 + tx]);
}

// ---------------------------------------------------------------------------
// Kernel 1: input repack fp32 NCHW -> bf16 [b][chunk8][h][w][cin32], all 4
// batches in one dispatch. Block = one (b,chunk,h) row; thread = w.
// ---------------------------------------------------------------------------
__global__ __launch_bounds__(256) void prep_kernel(const float* __restrict__ feats,
                                                   unsigned short* __restrict__ fb16) {
    const int bx = blockIdx.x;            // 8192: b(4) x chunk(8) x h(256)
    const int b = bx >> 11;
    const int chunk = (bx >> 8) & 7;
    const int h = bx & 255;
    const int w = threadIdx.x;
    const float* src = feats + (((size_t)b * 256 + chunk * 32) * 256 + h) * 256 + w;
    union { unsigned short u16[32]; short8 v8[4]; } p;
#pragma unroll
    for (int ci = 0; ci < 32; ++ci)
        p.u16[ci] = f2bf(src[(size_t)ci * 65536]);
    unsigned short* dst = fb16 + (size_t)b * 16777216
                        + ((size_t)(chunk * 256 + h) * 256 + w) * 32;
#pragma unroll
    for (int k = 0; k < 4; ++k)
        *(short8*)(dst + k * 8) = p.v8[k];
}

// ---------------------------------------------------------------------------
// Kernel 2: conv3x3 + bias + BN + ReLU, all batches, implicit GEMM.
// Block: 256 thr (4 waves), tile 128 couts x (4 rows x 64 cols) = 256 pixels.
// Wave: 64 couts x 128 pixels -> 32 MFMA per 8 LDS-b128 reads per tap.
// Double-buffered global_load_lds staging, ONE barrier per chunk.
// ---------------------------------------------------------------------------
__global__ __launch_bounds__(256, 2) void conv_bn_relu_kernel(
    const unsigned short* __restrict__ fb16,      // [b][chunk][h][w][cin32]
    const float* __restrict__ conv_b,
    const float* __restrict__ bn_gamma,
    const float* __restrict__ bn_beta,
    const float* __restrict__ bn_mean,
    const float* __restrict__ bn_var,
    const unsigned short* __restrict__ wprep,
    const unsigned short* __restrict__ zguard,
    unsigned short* __restrict__ feat_cl) {       // [b][h][w][128]

    // tile: 6 rows x 66 cols x 32 cin = 12672 shorts = 25344 B, double-buffered
    __shared__ __align__(16) unsigned short in_lds[2][12672];
    __shared__ float aL[128], bL[128];

    const int tid = threadIdx.x;
    const int bx  = blockIdx.x;            // 1024: b(4) x ht(64) x wt(4)
    const int b   = bx >> 8;
    const int rem = bx & 255;
    const int h0  = (rem >> 2) * 4;
    const int w0  = (rem & 3) * 64;

    if (tid < 128) {
        float s = bn_gamma[tid] * rsqrtf(bn_var[tid] + 1e-5f);
        aL[tid] = s;
        bL[tid] = (conv_b[tid] - bn_mean[tid]) * s + bn_beta[tid];
    }

    const int wave   = tid >> 6;
    const int lane   = tid & 63;
    const int q      = lane >> 4;
    const int l15    = lane & 15;
    const int cohalf = wave >> 1;          // 0/1: couts 0..63 / 64..127
    const int phalf  = wave & 1;           // 0/1: cols 0..31 / 32..63 of tile

    // ---- per-lane staging descriptors: 1584 16B units = 6 full + 48 tail --
    long off_s[7];
    int  lds_s[7];
    bool oob_s[7];
#pragma unroll
    for (int i = 0; i < 7; ++i) {
        int u = (i < 6) ? (i * 256 + tid) : (1536 + tid);
        int pix = u >> 2;
        int part = u & 3;
        int row = pix / 66;
        int col = pix - row * 66;
        int gh = h0 - 1 + row;
        int gw = w0 - 1 + col;
        oob_s[i] = ((unsigned)gh > 255u) || ((unsigned)gw > 255u);
        off_s[i] = (long)(gh * 256 + gw) * 32 + part * 8;
        lds_s[i] = u * 8;
    }

    const unsigned short* fbb = fb16 + (size_t)b * 16777216;

    float4v acc[4][8];
#pragma unroll
    for (int a = 0; a < 4; ++a)
#pragma unroll
        for (int p = 0; p < 8; ++p)
            acc[a][p] = (float4v){0.f, 0.f, 0.f, 0.f};

    // prologue: stage chunk 0 into buf 0
    {
        const unsigned short* fb = fbb;
#pragma unroll
        for (int i = 0; i < 6; ++i)
            gload_lds16(oob_s[i] ? zguard : (fb + off_s[i]), &in_lds[0][lds_s[i]]);
        if (tid < 48)
            gload_lds16(oob_s[6] ? zguard : (fb + off_s[6]), &in_lds[0][lds_s[6]]);
    }
    __syncthreads();   // vmcnt(0) drain -> buf0 ready

    for (int chunk = 0; chunk < 8; ++chunk) {
        // issue next chunk's DMA into the other buffer (overlaps with MFMA)
        if (chunk < 7) {
            const unsigned short* fb = fbb + (size_t)(chunk + 1) * 2097152;
            unsigned short* lb = in_lds[(chunk + 1) & 1];
#pragma unroll
            for (int i = 0; i < 6; ++i)
                gload_lds16(oob_s[i] ? zguard : (fb + off_s[i]), &lb[lds_s[i]]);
            if (tid < 48)
                gload_lds16(oob_s[6] ? zguard : (fb + off_s[6]), &lb[lds_s[6]]);
        }

        const unsigned short* lb = in_lds[chunk & 1];
#pragma unroll
        for (int tap = 0; tap < 9; ++tap) {
            const int dy = tap / 3, dx = tap - dy * 3;
            const short8* wpt = (const short8*)wprep
                              + ((chunk * 9 + tap) * 128 + cohalf * 64) * 4;
            short8 a0 = wpt[(l15     ) * 4 + q];
            short8 a1 = wpt[(l15 + 16) * 4 + q];
            short8 a2 = wpt[(l15 + 32) * 4 + q];
            short8 a3 = wpt[(l15 + 48) * 4 + q];
#pragma unroll
            for (int pt = 0; pt < 8; ++pt) {
                const int r  = pt >> 1;
                const int cc = phalf * 32 + (pt & 1) * 16 + l15 + dx;
                short8 bf = *(const short8*)&lb[((r + dy) * 66 + cc) * 32 + q * 8];
                acc[0][pt] = __builtin_amdgcn_mfma_f32_16x16x32_bf16(a0, bf, acc[0][pt], 0, 0, 0);
                acc[1][pt] = __builtin_amdgcn_mfma_f32_16x16x32_bf16(a1, bf, acc[1][pt], 0, 0, 0);
                acc[2][pt] = __builtin_amdgcn_mfma_f32_16x16x32_bf16(a2, bf, acc[2][pt], 0, 0, 0);
                acc[3][pt] = __builtin_amdgcn_mfma_f32_16x16x32_bf16(a3, bf, acc[3][pt], 0, 0, 0);
            }
        }
        if (chunk < 7) __syncthreads();   // waves done with buf, next DMA drained
    }

    // ---- epilogue: bias+BN+ReLU, channels-last bf16 store -----------------
    unsigned short* fcb = feat_cl + (size_t)b * 8388608;
#pragma unroll
    for (int ct = 0; ct < 4; ++ct) {
        const int co = cohalf * 64 + ct * 16 + q * 4;
        const float s0 = aL[co + 0], s1 = aL[co + 1];
        const float s2 = aL[co + 2], s3 = aL[co + 3];
        const float o0 = bL[co + 0], o1 = bL[co + 1];
        const float o2 = bL[co + 2], o3 = bL[co + 3];
#pragma unroll
        for (int pt = 0; pt < 8; ++pt) {
            const int r  = pt >> 1;
            const int cl = w0 + phalf * 32 + (pt & 1) * 16 + l15;
            float4v v = acc[ct][pt];
            unsigned short p0 = f2bf(fmaxf(v[0] * s0 + o0, 0.f));
            unsigned short p1 = f2bf(fmaxf(v[1] * s1 + o1, 0.f));
            unsigned short p2 = f2bf(fmaxf(v[2] * s2 + o2, 0.f));
            unsigned short p3 = f2bf(fmaxf(v[3] * s3 + o3, 0.f));
            unsigned long long pk = (unsigned long long)p0
                                  | ((unsigned long long)p1 << 16)
                                  | ((unsigned long long)p2 << 32)
                                  | ((unsigned long long)p3 << 48);
            size_t off = ((size_t)((h0 + r) * 256 + cl)) * 128 + co;
            *(unsigned long long*)(fcb + off) = pk;
        }
    }
}

// ---------------------------------------------------------------------------
// Kernel 3: masked bilinear RoI gather. Block = (roi, quarter of positions).
// ---------------------------------------------------------------------------
__global__ __launch_bounds__(256) void roi_gather_kernel(
    const float* __restrict__ rois,
    const float* __restrict__ masks,
    const unsigned long long* __restrict__ feat_u64,   // feat_cl as 4ch/8B
    float* __restrict__ out) {

    __shared__ int   offs[64][4];
    __shared__ float wts[64][4];

    const int blk = blockIdx.x;            // 512: roi(128) x q0(4)
    const int roi = blk >> 2;
    const int q0  = blk & 3;
    const int tid = threadIdx.x;

    const float* rp = rois + roi * 5;
    const int bi = (int)rp[0];
    int l_ = (int)(rp[1] * 0.25f - 1.0f);
    int t_ = (int)(rp[2] * 0.25f - 1.0f);
    int r_ = (int)(rp[3] * 0.25f + 1.0f);
    int b_ = (int)(rp[4] * 0.25f + 1.0f);
    l_ = imin(imax(l_, 0), 256); t_ = imin(imax(t_, 0), 256);
    r_ = imin(imax(r_, 0), 256); b_ = imin(imax(b_, 0), 256);
    const float ch = (float)(b_ - t_);
    const float cw = (float)(r_ - l_);
    const bool transpose = ch > 1.5f * cw;
    const int chi = imax(b_ - t_, 1);
    const int cwi = imax(r_ - l_, 1);
    const float vscale = ((r_ > l_) && (b_ > t_)) ? 1.f : 0.f;

    {
        const int pos_l  = tid >> 2;
        const int corner = tid & 3;
        const int pos = q0 * 64 + pos_l;
        const int i = pos >> 5, j = pos & 31;
        const float fi = (float)i + 0.5f, fj = (float)j + 0.5f;
        float V = transpose ? (fj * ch * (1.f / 32.f) - 0.5f)
                            : (fi * ch * (1.f / 8.f)  - 0.5f);
        float U = transpose ? (fi * cw * (1.f / 8.f)  - 0.5f)
                            : (fj * cw * (1.f / 32.f) - 0.5f);
        V = fmaxf(V, 0.f); U = fmaxf(U, 0.f);
        float vf = floorf(V), uf = floorf(U);
        int y0 = imin((int)vf, chi - 1); int y1 = imin(y0 + 1, chi - 1);
        int x0 = imin((int)uf, cwi - 1); int x1 = imin(x0 + 1, cwi - 1);
        float wy = V - vf, wx = U - uf;
        int ay = imin(imax(t_ + ((corner & 2) ? y1 : y0), 0), 255);
        int ax = imin(imax(l_ + ((corner & 1) ? x1 : x0), 0), 255);
        float wgt = ((corner & 2) ? wy : (1.f - wy)) * ((corner & 1) ? wx : (1.f - wx));
        wts[pos_l][corner]  = wgt * masks[(size_t)roi * 65536 + ay * 256 + ax] * vscale;
        offs[pos_l][corner] = (ay * 256 + ax) * 32;   // u64 units per pixel
    }
    __syncthreads();

    const int cq = tid & 31;              // channel quad: ch = 4*cq..4*cq+3
    const int pq = tid >> 5;              // 0..7
    // per-batch stride: 65536 pixels * 32 u64/pixel  (BUGFIX from R3: was *16)
    const unsigned long long* fb = feat_u64 + (size_t)bi * (65536ull * 32ull) + cq;
    float* op = out + (size_t)roi * 32768 + (size_t)cq * 4 * 256 + q0 * 64;

#pragma unroll 2
    for (int po = 0; po < 8; ++po) {
        const int pos_l = po * 8 + pq;
        float a0 = 0.f, a1 = 0.f, a2 = 0.f, a3 = 0.f;
#pragma unroll
        for (int k = 0; k < 4; ++k) {
            unsigned long long u = fb[offs[pos_l][k]];
            float w = wts[pos_l][k];
            a0 += w * __uint_as_float((unsigned)(u)       << 16);
            a1 += w * __uint_as_float((unsigned)(u >> 16) << 16);
            a2 += w * __uint_as_float((unsigned)(u >> 32) << 16);
            a3 += w * __uint_as_float((unsigned)(u >> 48) << 16);
        }
        op[pos_l]       = a0;
        op[pos_l + 256] = a1;
        op[pos_l + 512] = a2;
        op[pos_l + 768] = a3;
    }
}

// ---------------------------------------------------------------------------
extern "C" void kernel_launch(void* const* d_in, const int* in_sizes, int n_in,
                              void* d_out, int out_size, void* d_ws, size_t ws_size,
                              hipStream_t stream) {
    const float* feats    = (const float*)d_in[0];
    const float* rois     = (const float*)d_in[1];
    const float* masks    = (const float*)d_in[2];
    const float* conv_w   = (const float*)d_in[3];
    const float* conv_b   = (const float*)d_in[4];
    const float* bn_gamma = (const float*)d_in[5];
    const float* bn_beta  = (const float*)d_in[6];
    const float* bn_mean  = (const float*)d_in[7];
    const float* bn_var   = (const float*)d_in[8];
    float* out = (float*)d_out;

    // ws: [wprep 576KB][zguard][pad to 1MB][feat_cl 64MB][fb16 128MB]
    unsigned short* wprep   = (unsigned short*)d_ws;
    unsigned short* zguard  = (unsigned short*)((char*)d_ws + 0x90000);
    unsigned short* feat_cl = (unsigned short*)((char*)d_ws + (1ull << 20));
    unsigned short* fb16    = (unsigned short*)((char*)d_ws + (65ull << 20));

    hipLaunchKernelGGL(wprep_kernel, dim3(1152), dim3(256), 0, stream,
                       conv_w, wprep, zguard);
    hipLaunchKernelGGL(prep_kernel, dim3(8192), dim3(256), 0, stream, feats, fb16);
    hipLaunchKernelGGL(conv_bn_relu_kernel, dim3(1024), dim3(256), 0, stream,
                       fb16, conv_b, bn_gamma, bn_beta, bn_mean, bn_var,
                       wprep, zguard, feat_cl);
    hipLaunchKernelGGL(roi_gather_kernel, dim3(512), dim3(256), 0, stream,
                       rois, masks, (const unsigned long long*)feat_cl, out);
}